// Round 2
// baseline (1250.163 us; speedup 1.0000x reference)
//
#include <hip/hip_runtime.h>
#include <math.h>

// GPT-2 attention block on MI355X (gfx950), fp32 baseline.
// B=2, T=2048, C=1024, H=16, D=64.  M = B*T = 4096.
//
// Pipeline:
//   k1: qkv = x @ W_attn + b_attn   -> scatter to q/k/v in [B,H,T,D], q pre-scaled by 1/sqrt(D)
//   k2: flash attention (causal, online softmax) -> y in [B,T,C]
//   k3: out = y @ W_proj + b_proj
//
// attn_mask input (d_in[1]) is exactly triu(k=1) causal -> implemented structurally.

#define TSEQ 2048
#define CDIM 1024
#define NH   16
#define DH   64

// ---------------------------------------------------------------------------
// GEMM: out = A(MxK) @ B(KxN) + bias
//   EPI==0: plain row-major store into o0 (proj path)
//   EPI==1: qkv scatter: col -> (which, h, d); row -> (b, t); q scaled 0.125
// Tiles: BM=BN=128, BK=16; 256 threads; 8x8 microtile per thread.
// ---------------------------------------------------------------------------
template<int EPI>
__global__ __launch_bounds__(256) void gemm_k(const float* __restrict__ A,
                                              const float* __restrict__ B,
                                              const float* __restrict__ bias,
                                              float* __restrict__ o0,
                                              float* __restrict__ o1,
                                              float* __restrict__ o2,
                                              int M, int N, int K)
{
    __shared__ float As[16][132];   // As[k][m] (transposed A tile); pad->2-way max
    __shared__ float Bs[16][132];   // Bs[k][n]

    const int tid = threadIdx.x;
    const int tx = tid & 15, ty = tid >> 4;
    const int row0 = blockIdx.y * 128, col0 = blockIdx.x * 128;

    float acc[8][8];
#pragma unroll
    for (int i = 0; i < 8; ++i)
#pragma unroll
        for (int j = 0; j < 8; ++j) acc[i][j] = 0.f;

    const int fa0 = tid, fa1 = tid + 256;   // A tile: 512 float4; r=f>>2, kq=f&3
    const int fb0 = tid, fb1 = tid + 256;   // B tile: 512 float4; k=f>>5, nq=f&31

#define LOAD_A(dst, kbase, f) { const int r_ = (f) >> 2, kq_ = (f) & 3; \
        dst = *(const float4*)&A[(size_t)(row0 + r_) * K + (kbase) + kq_ * 4]; }
#define LOAD_B(dst, kbase, f) { const int kb_ = (f) >> 5, nq_ = (f) & 31; \
        dst = *(const float4*)&B[(size_t)((kbase) + kb_) * N + col0 + nq_ * 4]; }

    float4 ra0, ra1, rb0, rb1;
    LOAD_A(ra0, 0, fa0); LOAD_A(ra1, 0, fa1);
    LOAD_B(rb0, 0, fb0); LOAD_B(rb1, 0, fb1);

    for (int k0 = 0; k0 < K; k0 += 16) {
        __syncthreads();   // previous compute done before LDS overwrite
        {
            const int r0 = fa0 >> 2, kq0 = fa0 & 3;
            As[kq0*4+0][r0] = ra0.x; As[kq0*4+1][r0] = ra0.y;
            As[kq0*4+2][r0] = ra0.z; As[kq0*4+3][r0] = ra0.w;
            const int r1 = fa1 >> 2, kq1 = fa1 & 3;
            As[kq1*4+0][r1] = ra1.x; As[kq1*4+1][r1] = ra1.y;
            As[kq1*4+2][r1] = ra1.z; As[kq1*4+3][r1] = ra1.w;
            const int kb0 = fb0 >> 5, nq0 = fb0 & 31;
            *(float4*)&Bs[kb0][nq0*4] = rb0;
            const int kb1 = fb1 >> 5, nq1 = fb1 & 31;
            *(float4*)&Bs[kb1][nq1*4] = rb1;
        }
        __syncthreads();
        if (k0 + 16 < K) {            // prefetch next tile; latency hides under FMAs
            LOAD_A(ra0, k0 + 16, fa0); LOAD_A(ra1, k0 + 16, fa1);
            LOAD_B(rb0, k0 + 16, fb0); LOAD_B(rb1, k0 + 16, fb1);
        }
#pragma unroll
        for (int kk = 0; kk < 16; ++kk) {
            float4 a0 = *(const float4*)&As[kk][ty*8];
            float4 a1 = *(const float4*)&As[kk][ty*8+4];
            float4 b0 = *(const float4*)&Bs[kk][tx*8];
            float4 b1 = *(const float4*)&Bs[kk][tx*8+4];
            float av[8] = {a0.x,a0.y,a0.z,a0.w,a1.x,a1.y,a1.z,a1.w};
            float bv[8] = {b0.x,b0.y,b0.z,b0.w,b1.x,b1.y,b1.z,b1.w};
#pragma unroll
            for (int i = 0; i < 8; ++i)
#pragma unroll
                for (int j = 0; j < 8; ++j)
                    acc[i][j] = fmaf(av[i], bv[j], acc[i][j]);
        }
    }
#undef LOAD_A
#undef LOAD_B

    if (EPI == 0) {
#pragma unroll
        for (int i = 0; i < 8; ++i) {
            const int r = row0 + ty*8 + i;
#pragma unroll
            for (int j = 0; j < 8; ++j) {
                const int col = col0 + tx*8 + j;
                o0[(size_t)r * N + col] = acc[i][j] + bias[col];
            }
        }
    } else {
#pragma unroll
        for (int i = 0; i < 8; ++i) {
            const int r = row0 + ty*8 + i;
            const int bb = r >> 11;        // /T
            const int t  = r & (TSEQ - 1);
#pragma unroll
            for (int j = 0; j < 8; ++j) {
                const int col = col0 + tx*8 + j;
                const float v = acc[i][j] + bias[col];
                const int which = col >> 10;   // /C : 0=q 1=k 2=v
                const int c  = col & (CDIM - 1);
                const int h  = c >> 6, dd = c & (DH - 1);
                const int idx = ((bb*NH + h)*TSEQ + t)*DH + dd;
                if (which == 0)      o0[idx] = v * 0.125f;  // fold 1/sqrt(64)
                else if (which == 1) o1[idx] = v;
                else                 o2[idx] = v;
            }
        }
    }
}

// ---------------------------------------------------------------------------
// Flash attention, fp32, causal. One block = one (b,h) x 64-row q-tile.
// 256 threads: 16x16 grid, 4x4 microtile. Online softmax.
// q is pre-scaled by 1/sqrt(D).
// ---------------------------------------------------------------------------
__global__ __launch_bounds__(256) void attn_k(const float* __restrict__ Q,
                                              const float* __restrict__ K,
                                              const float* __restrict__ V,
                                              float* __restrict__ Y)
{
    __shared__ float Qs[64][65];   // pad 65 -> 2-way max on row-strided reads
    __shared__ float Ks[64][65];
    __shared__ float Vs[64][65];
    __shared__ float Ps[64][65];

    const int tid = threadIdx.x;
    const int tx = tid & 15, ty = tid >> 4;
    const int qt = blockIdx.x;         // q tile (64 rows)
    const int bh = blockIdx.y;         // b*NH + h
    const float* Qb = Q + (size_t)bh * TSEQ * DH;
    const float* Kb = K + (size_t)bh * TSEQ * DH;
    const float* Vb = V + (size_t)bh * TSEQ * DH;

    // load Q tile once: 1024 float4, 4 per thread; row=f>>4, d4=f&15
#pragma unroll
    for (int u = 0; u < 4; ++u) {
        const int f = tid + 256*u;
        const int r = f >> 4, d4 = f & 15;
        float4 qv = *(const float4*)&Qb[(size_t)(qt*64 + r)*DH + d4*4];
        Qs[r][d4*4+0] = qv.x; Qs[r][d4*4+1] = qv.y;
        Qs[r][d4*4+2] = qv.z; Qs[r][d4*4+3] = qv.w;
    }

    float O[4][4];
    float m_[4], l_[4];
#pragma unroll
    for (int i = 0; i < 4; ++i) {
        m_[i] = -1e30f; l_[i] = 0.f;
#pragma unroll
        for (int j = 0; j < 4; ++j) O[i][j] = 0.f;
    }

    for (int kt = 0; kt <= qt; ++kt) {
        __syncthreads();   // prev PV done before overwriting Ks/Vs
#pragma unroll
        for (int u = 0; u < 4; ++u) {
            const int f = tid + 256*u;
            const int r = f >> 4, d4 = f & 15;
            float4 kv = *(const float4*)&Kb[(size_t)(kt*64 + r)*DH + d4*4];
            Ks[r][d4*4+0] = kv.x; Ks[r][d4*4+1] = kv.y;
            Ks[r][d4*4+2] = kv.z; Ks[r][d4*4+3] = kv.w;
            float4 vv = *(const float4*)&Vb[(size_t)(kt*64 + r)*DH + d4*4];
            Vs[r][d4*4+0] = vv.x; Vs[r][d4*4+1] = vv.y;
            Vs[r][d4*4+2] = vv.z; Vs[r][d4*4+3] = vv.w;
        }
        __syncthreads();   // K/V (and on iter 0, Q) visible

        // S = Q @ K^T  (scale already folded into Q)
        float s[4][4];
#pragma unroll
        for (int i = 0; i < 4; ++i)
#pragma unroll
            for (int j = 0; j < 4; ++j) s[i][j] = 0.f;
#pragma unroll 8
        for (int d = 0; d < DH; ++d) {
            float a[4], b[4];
#pragma unroll
            for (int i = 0; i < 4; ++i) a[i] = Qs[ty*4+i][d];
#pragma unroll
            for (int j = 0; j < 4; ++j) b[j] = Ks[tx*4+j][d];
#pragma unroll
            for (int i = 0; i < 4; ++i)
#pragma unroll
                for (int j = 0; j < 4; ++j)
                    s[i][j] = fmaf(a[i], b[j], s[i][j]);
        }

        if (kt == qt) {   // causal mask within diagonal tile
#pragma unroll
            for (int i = 0; i < 4; ++i)
#pragma unroll
                for (int j = 0; j < 4; ++j)
                    if (tx*4+j > ty*4+i) s[i][j] = -1e30f;
        }

        // online softmax update
        float pm[4], mnew[4], alpha[4], ps[4];
#pragma unroll
        for (int i = 0; i < 4; ++i) {
            pm[i] = fmaxf(fmaxf(s[i][0], s[i][1]), fmaxf(s[i][2], s[i][3]));
#pragma unroll
            for (int mm = 1; mm < 16; mm <<= 1)
                pm[i] = fmaxf(pm[i], __shfl_xor(pm[i], mm, 16));
            mnew[i] = fmaxf(m_[i], pm[i]);
            alpha[i] = __expf(m_[i] - mnew[i]);
        }
        float p[4][4];
#pragma unroll
        for (int i = 0; i < 4; ++i) {
            ps[i] = 0.f;
#pragma unroll
            for (int j = 0; j < 4; ++j) {
                p[i][j] = __expf(s[i][j] - mnew[i]);
                ps[i] += p[i][j];
            }
#pragma unroll
            for (int mm = 1; mm < 16; mm <<= 1)
                ps[i] += __shfl_xor(ps[i], mm, 16);
            l_[i] = l_[i] * alpha[i] + ps[i];
            m_[i] = mnew[i];
#pragma unroll
            for (int j = 0; j < 4; ++j) {
                O[i][j] *= alpha[i];
                Ps[ty*4+i][tx*4+j] = p[i][j];
            }
        }
        __syncthreads();   // P visible

        // O += P @ V
#pragma unroll 8
        for (int kk = 0; kk < 64; ++kk) {
            float pv[4], vv[4];
#pragma unroll
            for (int i = 0; i < 4; ++i) pv[i] = Ps[ty*4+i][kk];
#pragma unroll
            for (int j = 0; j < 4; ++j) vv[j] = Vs[kk][tx*4+j];
#pragma unroll
            for (int i = 0; i < 4; ++i)
#pragma unroll
                for (int j = 0; j < 4; ++j)
                    O[i][j] = fmaf(pv[i], vv[j], O[i][j]);
        }
    }

    // write y in [B,T,C] layout: y[b][t][h*64 + d]
    const int b = bh >> 4, h = bh & 15;
#pragma unroll
    for (int i = 0; i < 4; ++i) {
        const int t = qt*64 + ty*4 + i;
        const float inv = 1.0f / l_[i];
#pragma unroll
        for (int j = 0; j < 4; ++j) {
            Y[((size_t)b*TSEQ + t)*CDIM + h*DH + tx*4 + j] = O[i][j] * inv;
        }
    }
}

// ---------------------------------------------------------------------------
extern "C" void kernel_launch(void* const* d_in, const int* in_sizes, int n_in,
                              void* d_out, int out_size, void* d_ws, size_t ws_size,
                              hipStream_t stream) {
    (void)in_sizes; (void)n_in; (void)out_size; (void)ws_size;
    const float* x      = (const float*)d_in[0];
    // d_in[1] = attn_mask (causal triu, implemented structurally)
    const float* W_attn = (const float*)d_in[2];
    const float* b_attn = (const float*)d_in[3];
    const float* W_proj = (const float*)d_in[4];
    const float* b_proj = (const float*)d_in[5];
    float* out = (float*)d_out;

    float* q = (float*)d_ws;             // [B,H,T,D] 4.19M floats
    float* k = q + 4194304;
    float* v = k + 4194304;
    float* y = v + 4194304;              // [B,T,C]   4.19M floats

    // qkv = x @ W_attn + b_attn, scattered to heads; M=4096 N=3072 K=1024
    gemm_k<1><<<dim3(24, 32), 256, 0, stream>>>(x, W_attn, b_attn, q, k, v,
                                                4096, 3072, 1024);
    // flash attention: grid (q-tiles, B*H)
    attn_k<<<dim3(TSEQ/64, 2*NH), 256, 0, stream>>>(q, k, v, y);
    // out = y @ W_proj + b_proj; M=4096 N=1024 K=1024
    gemm_k<0><<<dim3(8, 32), 256, 0, stream>>>(y, W_proj, b_proj, out,
                                               nullptr, nullptr,
                                               4096, 1024, 1024);
}

// Round 4
// 487.126 us; speedup vs baseline: 2.5664x; 2.5664x over previous
//
#include <hip/hip_runtime.h>
#include <math.h>

// GPT-2 attention block, bf16-MFMA pipeline. B=2, T=2048, C=1024, H=16, D=64.
// k0a: cast x -> bf16 [4096][1024]
// k0b: transpose-cast W_attn -> [3072][1024] bf16 ; W_proj -> [1024][1024] bf16
// k1 : qkv GEMM (bf16 MFMA, no LDS) -> q,k [b,h,t,d] bf16 (q pre-scaled 1/8), v^T [b,h,d,t] bf16
// k2 : flash attention (swapped-operand MFMA, barrier-free) -> y_hi,y_lo bf16 [4096][1024]
// k3 : proj GEMM, split-precision A (y_hi + y_lo) -> fp32 out + bias

#define TSEQ 2048
#define NHD  16
#define DH   64
#define CDIM 1024

typedef __attribute__((ext_vector_type(8))) short bf16x8;
typedef __attribute__((ext_vector_type(4))) float f32x4;

#define MFMA(a, b, c) __builtin_amdgcn_mfma_f32_16x16x32_bf16((a), (b), (c), 0, 0, 0)

__device__ __forceinline__ ushort f2bf(float f) {
    unsigned u = __builtin_bit_cast(unsigned, f);
    u += 0x7FFFu + ((u >> 16) & 1u);          // RNE
    return (ushort)(u >> 16);
}
__device__ __forceinline__ float bf2f(ushort h) {
    unsigned u = ((unsigned)h) << 16;
    return __builtin_bit_cast(float, u);
}

// ---------------------------------------------------------------- prepass ---
__global__ __launch_bounds__(256) void cast_k(const float* __restrict__ in,
                                              ushort* __restrict__ out, int n4) {
    int i = blockIdx.x * 256 + threadIdx.x;
    const int stride = gridDim.x * 256;
    for (; i < n4; i += stride) {
        float4 f = ((const float4*)in)[i];
        ushort4 o;
        o.x = f2bf(f.x); o.y = f2bf(f.y); o.z = f2bf(f.z); o.w = f2bf(f.w);
        ((ushort4*)out)[i] = o;
    }
}

// in fp32 [R][C] -> out bf16 [C][R]
__global__ __launch_bounds__(256) void transpose_k(const float* __restrict__ in,
                                                   ushort* __restrict__ out,
                                                   int R, int C) {
    __shared__ float t[32][33];
    const int tx = threadIdx.x, ty = threadIdx.y;     // 32 x 8
    const int c0 = blockIdx.x * 32, r0 = blockIdx.y * 32;
#pragma unroll
    for (int i = 0; i < 4; ++i)
        t[ty + i * 8][tx] = in[(size_t)(r0 + ty + i * 8) * C + c0 + tx];
    __syncthreads();
#pragma unroll
    for (int i = 0; i < 4; ++i)
        out[(size_t)(c0 + ty + i * 8) * R + r0 + tx] = f2bf(t[tx][ty + i * 8]);
}

// ------------------------------------------------------------------- qkv ----
// X[4096][1024] bf16, Wt[3072][1024] bf16 (n-major). 128x128 tile, 4 waves 2x2.
__global__ __launch_bounds__(256) void qkv_k(const ushort* __restrict__ X,
                                             const ushort* __restrict__ Wt,
                                             const float* __restrict__ bias,
                                             ushort* __restrict__ qb,
                                             ushort* __restrict__ kb,
                                             ushort* __restrict__ vtb) {
    const int fid = blockIdx.x;                 // 768 = 8 * 96 (bijective swizzle)
    const int nf = (fid & 7) * 96 + (fid >> 3);
    const int mt = nf / 24, nt = nf % 24;
    const int m0 = mt * 128, n0 = nt * 128;
    const int tid = threadIdx.x, lane = tid & 63, w = tid >> 6;
    const int l15 = lane & 15, g = lane >> 4;
    const int wm = w >> 1, wn = w & 1;

    const ushort* Ar[4]; const ushort* Br[4];
#pragma unroll
    for (int s = 0; s < 4; ++s) {
        Ar[s] = X  + (size_t)(m0 + wm * 64 + s * 16 + l15) * 1024 + g * 8;
        Br[s] = Wt + (size_t)(n0 + wn * 64 + s * 16 + l15) * 1024 + g * 8;
    }
    f32x4 acc[4][4] = {};
    bf16x8 a[4], b[4], a2[4], b2[4];
#pragma unroll
    for (int s = 0; s < 4; ++s) { a[s] = *(const bf16x8*)(Ar[s]); b[s] = *(const bf16x8*)(Br[s]); }

    for (int kk = 0; kk < 1024; kk += 32) {
        if (kk + 32 < 1024) {
#pragma unroll
            for (int s = 0; s < 4; ++s) {
                a2[s] = *(const bf16x8*)(Ar[s] + kk + 32);
                b2[s] = *(const bf16x8*)(Br[s] + kk + 32);
            }
        }
#pragma unroll
        for (int i = 0; i < 4; ++i)
#pragma unroll
            for (int j = 0; j < 4; ++j)
                acc[i][j] = MFMA(a[i], b[j], acc[i][j]);
#pragma unroll
        for (int s = 0; s < 4; ++s) { a[s] = a2[s]; b[s] = b2[s]; }
    }
    // epilogue: D col = lane&15 (n), row = g*4+reg (m within 16-subtile)
#pragma unroll
    for (int j = 0; j < 4; ++j) {
        const int n = n0 + wn * 64 + j * 16 + l15;
        const float bv = bias[n];
        const int which = n >> 10;
        const int c = n & 1023, h = c >> 6, d = c & 63;
#pragma unroll
        for (int i = 0; i < 4; ++i)
#pragma unroll
            for (int r = 0; r < 4; ++r) {
                const int m = m0 + wm * 64 + i * 16 + g * 4 + r;
                const int bb = m >> 11, t = m & 2047;
                const float val = acc[i][j][r] + bv;
                const int bh = bb * NHD + h;
                if (which == 0)
                    qb[((size_t)bh * TSEQ + t) * 64 + d] = f2bf(val * 0.125f);
                else if (which == 1)
                    kb[((size_t)bh * TSEQ + t) * 64 + d] = f2bf(val);
                else
                    vtb[((size_t)bh * 64 + d) * TSEQ + t] = f2bf(val);
            }
    }
}

// ------------------------------------------------------------- attention ----
// Swapped QK^T: S^T = K·Q^T (D: col=lane&15=q, row=g*4+reg=k-within-16).
// PV as O^T = V^T · P^T. Barrier-free; per-wave private P bounce in LDS.
__global__ __launch_bounds__(256) void attn_k(const ushort* __restrict__ Q,
                                              const ushort* __restrict__ K,
                                              const ushort* __restrict__ VT,
                                              ushort* __restrict__ Yh,
                                              ushort* __restrict__ Yl) {
    __shared__ ushort P[4][16][72];    // [wave][q][k] (+pad)
    const int fid = blockIdx.y * 32 + blockIdx.x;       // 1024 = 8 * 128
    const int nf = (fid & 7) * 128 + (fid >> 3);        // 4 heads per XCD -> 2MB L2 set
    const int qt = nf & 31, bh = nf >> 5;
    const int tid = threadIdx.x, lane = tid & 63, w = tid >> 6;
    const int l15 = lane & 15, g = lane >> 4;
    const int q0 = qt * 64 + w * 16;

    const ushort* Qb = Q  + (size_t)bh * TSEQ * 64;
    const ushort* Kb = K  + (size_t)bh * TSEQ * 64;
    const ushort* Vb = VT + (size_t)bh * 64 * TSEQ;

    bf16x8 qf0 = *(const bf16x8*)(Qb + (size_t)(q0 + l15) * 64 + g * 8);
    bf16x8 qf1 = *(const bf16x8*)(Qb + (size_t)(q0 + l15) * 64 + 32 + g * 8);

    f32x4 o[4] = {};
    float m_run = -INFINITY, l_run = 0.f;

    for (int kv0 = 0; kv0 <= qt * 64; kv0 += 64) {
        bf16x8 ak[4][2], av[4][2];
#pragma unroll
        for (int s = 0; s < 4; ++s) {        // K rows (keys), V^T rows (d)
            const ushort* kr = Kb + (size_t)(kv0 + s * 16 + l15) * 64 + g * 8;
            ak[s][0] = *(const bf16x8*)(kr);
            ak[s][1] = *(const bf16x8*)(kr + 32);
            const ushort* vr = Vb + (size_t)(s * 16 + l15) * TSEQ + kv0 + g * 8;
            av[s][0] = *(const bf16x8*)(vr);
            av[s][1] = *(const bf16x8*)(vr + 32);
        }
        f32x4 s4[4] = {};
#pragma unroll
        for (int s = 0; s < 4; ++s) {
            s4[s] = MFMA(ak[s][0], qf0, s4[s]);
            s4[s] = MFMA(ak[s][1], qf1, s4[s]);
        }
        if (kv0 + 63 > q0) {                 // only the diagonal tile
#pragma unroll
            for (int s = 0; s < 4; ++s)
#pragma unroll
                for (int r = 0; r < 4; ++r) {
                    const int kg = kv0 + s * 16 + g * 4 + r;
                    if (kg > q0 + l15) s4[s][r] = -INFINITY;
                }
        }
        float mx = -INFINITY;
#pragma unroll
        for (int s = 0; s < 4; ++s)
#pragma unroll
            for (int r = 0; r < 4; ++r) mx = fmaxf(mx, s4[s][r]);
        mx = fmaxf(mx, __shfl_xor(mx, 16));
        mx = fmaxf(mx, __shfl_xor(mx, 32));
        const float mnew = fmaxf(m_run, mx);
        const float alpha = __expf(m_run - mnew);
        float lsum = 0.f;
#pragma unroll
        for (int s = 0; s < 4; ++s)
#pragma unroll
            for (int r = 0; r < 4; ++r) {
                const float p = __expf(s4[s][r] - mnew);
                lsum += p;
                P[w][l15][s * 16 + g * 4 + r] = f2bf(p);
            }
        lsum += __shfl_xor(lsum, 16);
        lsum += __shfl_xor(lsum, 32);
        l_run = l_run * alpha + lsum;
        m_run = mnew;
#pragma unroll
        for (int s = 0; s < 4; ++s)
#pragma unroll
            for (int r = 0; r < 4; ++r) o[s][r] *= alpha;
        // same-wave LDS write->read: DS pipe is in-order per wave, no barrier
        bf16x8 pb0 = *(const bf16x8*)&P[w][l15][g * 8];
        bf16x8 pb1 = *(const bf16x8*)&P[w][l15][32 + g * 8];
#pragma unroll
        for (int s = 0; s < 4; ++s) {
            o[s] = MFMA(av[s][0], pb0, o[s]);
            o[s] = MFMA(av[s][1], pb1, o[s]);
        }
    }
    const float inv = 1.f / l_run;
    const int t = q0 + l15;
    const size_t base = ((size_t)(bh >> 4) * TSEQ + t) * CDIM + (bh & 15) * 64;
#pragma unroll
    for (int s = 0; s < 4; ++s) {
        ushort4 hv, lv;
        float v;
        v = o[s][0] * inv; hv.x = f2bf(v); lv.x = f2bf(v - bf2f(hv.x));
        v = o[s][1] * inv; hv.y = f2bf(v); lv.y = f2bf(v - bf2f(hv.y));
        v = o[s][2] * inv; hv.z = f2bf(v); lv.z = f2bf(v - bf2f(hv.z));
        v = o[s][3] * inv; hv.w = f2bf(v); lv.w = f2bf(v - bf2f(hv.w));
        *(ushort4*)&Yh[base + s * 16 + g * 4] = hv;
        *(ushort4*)&Yl[base + s * 16 + g * 4] = lv;
    }
}

// ------------------------------------------------------------------ proj ----
// out = (Yh + Yl) @ W_proj + b, split-precision A. Wt n-major [1024][1024].
__global__ __launch_bounds__(256) void proj_k(const ushort* __restrict__ Yh,
                                              const ushort* __restrict__ Yl,
                                              const ushort* __restrict__ Wt,
                                              const float* __restrict__ bias,
                                              float* __restrict__ out) {
    const int fid = blockIdx.x;                 // 256 = 8 * 32
    const int nf = (fid & 7) * 32 + (fid >> 3);
    const int mt = nf >> 3, nt = nf & 7;
    const int m0 = mt * 128, n0 = nt * 128;
    const int tid = threadIdx.x, lane = tid & 63, w = tid >> 6;
    const int l15 = lane & 15, g = lane >> 4;
    const int wm = w >> 1, wn = w & 1;

    const ushort* Ah[4]; const ushort* Al[4]; const ushort* Br[4];
#pragma unroll
    for (int s = 0; s < 4; ++s) {
        const size_t arow = (size_t)(m0 + wm * 64 + s * 16 + l15) * 1024 + g * 8;
        Ah[s] = Yh + arow;
        Al[s] = Yl + arow;
        Br[s] = Wt + (size_t)(n0 + wn * 64 + s * 16 + l15) * 1024 + g * 8;
    }
    f32x4 acc[4][4] = {};
#pragma unroll 2
    for (int kk = 0; kk < 1024; kk += 32) {
        bf16x8 ah[4], al[4], b[4];
#pragma unroll
        for (int s = 0; s < 4; ++s) {
            ah[s] = *(const bf16x8*)(Ah[s] + kk);
            al[s] = *(const bf16x8*)(Al[s] + kk);
            b[s]  = *(const bf16x8*)(Br[s] + kk);
        }
#pragma unroll
        for (int i = 0; i < 4; ++i)
#pragma unroll
            for (int j = 0; j < 4; ++j) {
                acc[i][j] = MFMA(ah[i], b[j], acc[i][j]);
                acc[i][j] = MFMA(al[i], b[j], acc[i][j]);
            }
    }
#pragma unroll
    for (int j = 0; j < 4; ++j) {
        const int n = n0 + wn * 64 + j * 16 + l15;
        const float bv = bias[n];
#pragma unroll
        for (int i = 0; i < 4; ++i)
#pragma unroll
            for (int r = 0; r < 4; ++r) {
                const int m = m0 + wm * 64 + i * 16 + g * 4 + r;
                out[(size_t)m * 1024 + n] = acc[i][j][r] + bv;
            }
    }
}

// ---------------------------------------------------------------------------
extern "C" void kernel_launch(void* const* d_in, const int* in_sizes, int n_in,
                              void* d_out, int out_size, void* d_ws, size_t ws_size,
                              hipStream_t stream) {
    (void)in_sizes; (void)n_in; (void)out_size; (void)ws_size;
    const float* x      = (const float*)d_in[0];
    // d_in[1] = attn_mask (causal triu -> structural)
    const float* W_attn = (const float*)d_in[2];
    const float* b_attn = (const float*)d_in[3];
    const float* W_proj = (const float*)d_in[4];
    const float* b_proj = (const float*)d_in[5];
    float* out = (float*)d_out;

    ushort* xb  = (ushort*)d_ws;          // 4096*1024
    ushort* wta = xb  + 4194304;          // 3072*1024
    ushort* wtp = wta + 3145728;          // 1024*1024
    ushort* qb  = wtp + 1048576;          // [32][2048][64]
    ushort* kb  = qb  + 4194304;
    ushort* vtb = kb  + 4194304;          // [32][64][2048]
    ushort* yh  = vtb + 4194304;          // [4096][1024]
    ushort* yl  = yh  + 4194304;

    cast_k<<<1024, 256, 0, stream>>>(x, xb, 4194304 / 4);
    transpose_k<<<dim3(96, 32), dim3(32, 8), 0, stream>>>(W_attn, wta, 1024, 3072);
    transpose_k<<<dim3(32, 32), dim3(32, 8), 0, stream>>>(W_proj, wtp, 1024, 1024);
    qkv_k<<<768, 256, 0, stream>>>(xb, wta, b_attn, qb, kb, vtb);
    attn_k<<<dim3(32, 32), 256, 0, stream>>>(qb, kb, vtb, yh, yl);
    proj_k<<<256, 256, 0, stream>>>(yh, yl, wtp, b_proj, out);
}

// Round 5
// 405.955 us; speedup vs baseline: 3.0796x; 1.2000x over previous
//
#include <hip/hip_runtime.h>
#include <math.h>

// GPT-2 attention block, bf16-MFMA pipeline. B=2, T=2048, C=1024, H=16, D=64.
// R5: attention restructured for occupancy — 4096 single-wave blocks (whole
// grid co-resident), K-tile double-buffer, vectorized P-bounce writes.

#define TSEQ 2048
#define NHD  16
#define DH   64
#define CDIM 1024

typedef __attribute__((ext_vector_type(8))) short bf16x8;
typedef __attribute__((ext_vector_type(4))) float f32x4;

#define MFMA(a, b, c) __builtin_amdgcn_mfma_f32_16x16x32_bf16((a), (b), (c), 0, 0, 0)

__device__ __forceinline__ ushort f2bf(float f) {
    unsigned u = __builtin_bit_cast(unsigned, f);
    u += 0x7FFFu + ((u >> 16) & 1u);          // RNE
    return (ushort)(u >> 16);
}
__device__ __forceinline__ float bf2f(ushort h) {
    unsigned u = ((unsigned)h) << 16;
    return __builtin_bit_cast(float, u);
}

// ---------------------------------------------------------------- prepass ---
__global__ __launch_bounds__(256) void cast_k(const float* __restrict__ in,
                                              ushort* __restrict__ out, int n4) {
    int i = blockIdx.x * 256 + threadIdx.x;
    const int stride = gridDim.x * 256;
    for (; i < n4; i += stride) {
        float4 f = ((const float4*)in)[i];
        ushort4 o;
        o.x = f2bf(f.x); o.y = f2bf(f.y); o.z = f2bf(f.z); o.w = f2bf(f.w);
        ((ushort4*)out)[i] = o;
    }
}

// in fp32 [R][C] -> out bf16 [C][R]
__global__ __launch_bounds__(256) void transpose_k(const float* __restrict__ in,
                                                   ushort* __restrict__ out,
                                                   int R, int C) {
    __shared__ float t[32][33];
    const int tx = threadIdx.x, ty = threadIdx.y;     // 32 x 8
    const int c0 = blockIdx.x * 32, r0 = blockIdx.y * 32;
#pragma unroll
    for (int i = 0; i < 4; ++i)
        t[ty + i * 8][tx] = in[(size_t)(r0 + ty + i * 8) * C + c0 + tx];
    __syncthreads();
#pragma unroll
    for (int i = 0; i < 4; ++i)
        out[(size_t)(c0 + ty + i * 8) * R + r0 + tx] = f2bf(t[tx][ty + i * 8]);
}

// ------------------------------------------------------------------- qkv ----
// X[4096][1024] bf16, Wt[3072][1024] bf16 (n-major). 128x128 tile, 4 waves 2x2.
__global__ __launch_bounds__(256) void qkv_k(const ushort* __restrict__ X,
                                             const ushort* __restrict__ Wt,
                                             const float* __restrict__ bias,
                                             ushort* __restrict__ qb,
                                             ushort* __restrict__ kb,
                                             ushort* __restrict__ vtb) {
    const int fid = blockIdx.x;                 // 768 = 8 * 96 (bijective swizzle)
    const int nf = (fid & 7) * 96 + (fid >> 3);
    const int mt = nf / 24, nt = nf % 24;
    const int m0 = mt * 128, n0 = nt * 128;
    const int tid = threadIdx.x, lane = tid & 63, w = tid >> 6;
    const int l15 = lane & 15, g = lane >> 4;
    const int wm = w >> 1, wn = w & 1;

    const ushort* Ar[4]; const ushort* Br[4];
#pragma unroll
    for (int s = 0; s < 4; ++s) {
        Ar[s] = X  + (size_t)(m0 + wm * 64 + s * 16 + l15) * 1024 + g * 8;
        Br[s] = Wt + (size_t)(n0 + wn * 64 + s * 16 + l15) * 1024 + g * 8;
    }
    f32x4 acc[4][4] = {};
    bf16x8 a[4], b[4], a2[4], b2[4];
#pragma unroll
    for (int s = 0; s < 4; ++s) { a[s] = *(const bf16x8*)(Ar[s]); b[s] = *(const bf16x8*)(Br[s]); }

    for (int kk = 0; kk < 1024; kk += 32) {
        if (kk + 32 < 1024) {
#pragma unroll
            for (int s = 0; s < 4; ++s) {
                a2[s] = *(const bf16x8*)(Ar[s] + kk + 32);
                b2[s] = *(const bf16x8*)(Br[s] + kk + 32);
            }
        }
#pragma unroll
        for (int i = 0; i < 4; ++i)
#pragma unroll
            for (int j = 0; j < 4; ++j)
                acc[i][j] = MFMA(a[i], b[j], acc[i][j]);
#pragma unroll
        for (int s = 0; s < 4; ++s) { a[s] = a2[s]; b[s] = b2[s]; }
    }
    // epilogue: D col = lane&15 (n), row = g*4+reg (m within 16-subtile)
#pragma unroll
    for (int j = 0; j < 4; ++j) {
        const int n = n0 + wn * 64 + j * 16 + l15;
        const float bv = bias[n];
        const int which = n >> 10;
        const int c = n & 1023, h = c >> 6, d = c & 63;
#pragma unroll
        for (int i = 0; i < 4; ++i)
#pragma unroll
            for (int r = 0; r < 4; ++r) {
                const int m = m0 + wm * 64 + i * 16 + g * 4 + r;
                const int bb = m >> 11, t = m & 2047;
                const float val = acc[i][j][r] + bv;
                const int bh = bb * NHD + h;
                if (which == 0)
                    qb[((size_t)bh * TSEQ + t) * 64 + d] = f2bf(val * 0.125f);
                else if (which == 1)
                    kb[((size_t)bh * TSEQ + t) * 64 + d] = f2bf(val);
                else
                    vtb[((size_t)bh * 64 + d) * TSEQ + t] = f2bf(val);
            }
    }
}

// ------------------------------------------------------------- attention ----
// Swapped QK^T: S^T = K·Q^T (D: col=lane&15=q, row=g*4+reg=k-within-16).
// PV as O^T = V^T · P^T. Barrier-free; per-wave private P bounce in LDS.
// One wave per block, 16 q-rows; whole grid (4096 blocks) co-resident.
__global__ __launch_bounds__(64, 4) void attn_k(const ushort* __restrict__ Q,
                                                const ushort* __restrict__ K,
                                                const ushort* __restrict__ VT,
                                                ushort* __restrict__ Yh,
                                                ushort* __restrict__ Yl) {
    __shared__ ushort P[16][72];       // [q][k] (+pad)
    const int fid = blockIdx.x;        // 4096 = 8 XCD * 512 (4 heads/XCD -> 2MB L2)
    const int nf = (fid & 7) * 512 + (fid >> 3);
    const int bh = nf >> 7, q16 = nf & 127;
    const int lane = threadIdx.x & 63;
    const int l15 = lane & 15, g = lane >> 4;
    const int q0 = q16 * 16;

    const ushort* Qb = Q  + (size_t)bh * TSEQ * 64;
    const ushort* Kb = K  + (size_t)bh * TSEQ * 64;
    const ushort* Vb = VT + (size_t)bh * 64 * TSEQ;

    bf16x8 qf0 = *(const bf16x8*)(Qb + (size_t)(q0 + l15) * 64 + g * 8);
    bf16x8 qf1 = *(const bf16x8*)(Qb + (size_t)(q0 + l15) * 64 + 32 + g * 8);

    f32x4 o[4] = {};
    float m_run = -INFINITY, l_run = 0.f;
    const int nT = (q0 + 15) / 64 + 1;   // kv tiles (64-wide)

    bf16x8 ak[4][2], ak2[4][2], av[4][2];
#pragma unroll
    for (int s = 0; s < 4; ++s) {        // K tile 0
        const ushort* kr = Kb + (size_t)(s * 16 + l15) * 64 + g * 8;
        ak[s][0] = *(const bf16x8*)(kr);
        ak[s][1] = *(const bf16x8*)(kr + 32);
    }

    for (int t = 0; t < nT; ++t) {
        const int kv0 = t * 64;
        // V for current tile — issue early, hides under S-MFMA+softmax
#pragma unroll
        for (int s = 0; s < 4; ++s) {
            const ushort* vr = Vb + (size_t)(s * 16 + l15) * TSEQ + kv0 + g * 8;
            av[s][0] = *(const bf16x8*)(vr);
            av[s][1] = *(const bf16x8*)(vr + 32);
        }
        // prefetch next K tile (double-buffer)
        if (t + 1 < nT) {
#pragma unroll
            for (int s = 0; s < 4; ++s) {
                const ushort* kr = Kb + (size_t)(kv0 + 64 + s * 16 + l15) * 64 + g * 8;
                ak2[s][0] = *(const bf16x8*)(kr);
                ak2[s][1] = *(const bf16x8*)(kr + 32);
            }
        }
        f32x4 s4[4] = {};
#pragma unroll
        for (int s = 0; s < 4; ++s) {
            s4[s] = MFMA(ak[s][0], qf0, s4[s]);
            s4[s] = MFMA(ak[s][1], qf1, s4[s]);
        }
        if (kv0 + 63 > q0) {             // only the diagonal-overlapping tile
#pragma unroll
            for (int s = 0; s < 4; ++s)
#pragma unroll
                for (int r = 0; r < 4; ++r) {
                    const int kg = kv0 + s * 16 + g * 4 + r;
                    if (kg > q0 + l15) s4[s][r] = -INFINITY;
                }
        }
        float mx = -INFINITY;
#pragma unroll
        for (int s = 0; s < 4; ++s)
#pragma unroll
            for (int r = 0; r < 4; ++r) mx = fmaxf(mx, s4[s][r]);
        mx = fmaxf(mx, __shfl_xor(mx, 16));
        mx = fmaxf(mx, __shfl_xor(mx, 32));
        const float mnew = fmaxf(m_run, mx);
        const float alpha = __expf(m_run - mnew);
        float lsum = 0.f;
#pragma unroll
        for (int s = 0; s < 4; ++s) {
            float p0 = __expf(s4[s][0] - mnew);
            float p1 = __expf(s4[s][1] - mnew);
            float p2 = __expf(s4[s][2] - mnew);
            float p3 = __expf(s4[s][3] - mnew);
            lsum += (p0 + p1) + (p2 + p3);
            ushort4 pw;
            pw.x = f2bf(p0); pw.y = f2bf(p1); pw.z = f2bf(p2); pw.w = f2bf(p3);
            *(ushort4*)&P[l15][s * 16 + g * 4] = pw;   // k = s*16+g*4+r
        }
        lsum += __shfl_xor(lsum, 16);
        lsum += __shfl_xor(lsum, 32);
        l_run = l_run * alpha + lsum;
        m_run = mnew;
#pragma unroll
        for (int s = 0; s < 4; ++s)
#pragma unroll
            for (int r = 0; r < 4; ++r) o[s][r] *= alpha;
        // same-wave LDS write->read: DS pipe in-order per wave, no barrier
        bf16x8 pb0 = *(const bf16x8*)&P[l15][g * 8];
        bf16x8 pb1 = *(const bf16x8*)&P[l15][32 + g * 8];
#pragma unroll
        for (int s = 0; s < 4; ++s) {
            o[s] = MFMA(av[s][0], pb0, o[s]);
            o[s] = MFMA(av[s][1], pb1, o[s]);
        }
#pragma unroll
        for (int s = 0; s < 4; ++s) { ak[s][0] = ak2[s][0]; ak[s][1] = ak2[s][1]; }
    }
    const float inv = 1.f / l_run;
    const int t = q0 + l15;
    const size_t base = ((size_t)(bh >> 4) * TSEQ + t) * CDIM + (bh & 15) * 64;
#pragma unroll
    for (int s = 0; s < 4; ++s) {
        ushort4 hv, lv;
        float v;
        v = o[s][0] * inv; hv.x = f2bf(v); lv.x = f2bf(v - bf2f(hv.x));
        v = o[s][1] * inv; hv.y = f2bf(v); lv.y = f2bf(v - bf2f(hv.y));
        v = o[s][2] * inv; hv.z = f2bf(v); lv.z = f2bf(v - bf2f(hv.z));
        v = o[s][3] * inv; hv.w = f2bf(v); lv.w = f2bf(v - bf2f(hv.w));
        *(ushort4*)&Yh[base + s * 16 + g * 4] = hv;
        *(ushort4*)&Yl[base + s * 16 + g * 4] = lv;
    }
}

// ------------------------------------------------------------------ proj ----
// out = (Yh + Yl) @ W_proj + b, split-precision A. Wt n-major [1024][1024].
__global__ __launch_bounds__(256) void proj_k(const ushort* __restrict__ Yh,
                                              const ushort* __restrict__ Yl,
                                              const ushort* __restrict__ Wt,
                                              const float* __restrict__ bias,
                                              float* __restrict__ out) {
    const int fid = blockIdx.x;                 // 256 = 8 * 32
    const int nf = (fid & 7) * 32 + (fid >> 3);
    const int mt = nf >> 3, nt = nf & 7;
    const int m0 = mt * 128, n0 = nt * 128;
    const int tid = threadIdx.x, lane = tid & 63, w = tid >> 6;
    const int l15 = lane & 15, g = lane >> 4;
    const int wm = w >> 1, wn = w & 1;

    const ushort* Ah[4]; const ushort* Al[4]; const ushort* Br[4];
#pragma unroll
    for (int s = 0; s < 4; ++s) {
        const size_t arow = (size_t)(m0 + wm * 64 + s * 16 + l15) * 1024 + g * 8;
        Ah[s] = Yh + arow;
        Al[s] = Yl + arow;
        Br[s] = Wt + (size_t)(n0 + wn * 64 + s * 16 + l15) * 1024 + g * 8;
    }
    f32x4 acc[4][4] = {};
#pragma unroll 2
    for (int kk = 0; kk < 1024; kk += 32) {
        bf16x8 ah[4], al[4], b[4];
#pragma unroll
        for (int s = 0; s < 4; ++s) {
            ah[s] = *(const bf16x8*)(Ah[s] + kk);
            al[s] = *(const bf16x8*)(Al[s] + kk);
            b[s]  = *(const bf16x8*)(Br[s] + kk);
        }
#pragma unroll
        for (int i = 0; i < 4; ++i)
#pragma unroll
            for (int j = 0; j < 4; ++j) {
                acc[i][j] = MFMA(ah[i], b[j], acc[i][j]);
                acc[i][j] = MFMA(al[i], b[j], acc[i][j]);
            }
    }
#pragma unroll
    for (int j = 0; j < 4; ++j) {
        const int n = n0 + wn * 64 + j * 16 + l15;
        const float bv = bias[n];
#pragma unroll
        for (int i = 0; i < 4; ++i)
#pragma unroll
            for (int r = 0; r < 4; ++r) {
                const int m = m0 + wm * 64 + i * 16 + g * 4 + r;
                out[(size_t)m * 1024 + n] = acc[i][j][r] + bv;
            }
    }
}

// ---------------------------------------------------------------------------
extern "C" void kernel_launch(void* const* d_in, const int* in_sizes, int n_in,
                              void* d_out, int out_size, void* d_ws, size_t ws_size,
                              hipStream_t stream) {
    (void)in_sizes; (void)n_in; (void)out_size; (void)ws_size;
    const float* x      = (const float*)d_in[0];
    // d_in[1] = attn_mask (causal triu -> structural)
    const float* W_attn = (const float*)d_in[2];
    const float* b_attn = (const float*)d_in[3];
    const float* W_proj = (const float*)d_in[4];
    const float* b_proj = (const float*)d_in[5];
    float* out = (float*)d_out;

    ushort* xb  = (ushort*)d_ws;          // 4096*1024
    ushort* wta = xb  + 4194304;          // 3072*1024
    ushort* wtp = wta + 3145728;          // 1024*1024
    ushort* qb  = wtp + 1048576;          // [32][2048][64]
    ushort* kb  = qb  + 4194304;
    ushort* vtb = kb  + 4194304;          // [32][64][2048]
    ushort* yh  = vtb + 4194304;          // [4096][1024]
    ushort* yl  = yh  + 4194304;

    cast_k<<<1024, 256, 0, stream>>>(x, xb, 4194304 / 4);
    transpose_k<<<dim3(96, 32), dim3(32, 8), 0, stream>>>(W_attn, wta, 1024, 3072);
    transpose_k<<<dim3(32, 32), dim3(32, 8), 0, stream>>>(W_proj, wtp, 1024, 1024);
    qkv_k<<<768, 256, 0, stream>>>(xb, wta, b_attn, qb, kb, vtb);
    attn_k<<<4096, 64, 0, stream>>>(qb, kb, vtb, yh, yl);
    proj_k<<<256, 256, 0, stream>>>(yh, yl, wtp, b_proj, out);
}